// Round 16
// baseline (156.116 us; speedup 1.0000x reference)
//
#include <hip/hip_runtime.h>
#include <hip/hip_fp8.h>
#include <stdint.h>

#define N_CLS 8192
#define FEAT  512                           // elements; fp8 -> 512 B per row
#define BATCH 1024
#define NTI   32                            // 256-row tiles
#define NTJ   64                            // 128-col tiles
#define NPAIR 1056                          // #{(i,j): j in [2i, 64)} = 8*132
#define NSLOT 8                             // FEAT/64 (K=64 per slot)
#define SLOTB 24576                         // bytes/slot: A 256*64 + B 128*64
#define UNITSC 0x7f7f7f7f                   // E8M0 unit scales (2^0)

typedef __attribute__((ext_vector_type(4))) float f32x4;
typedef __attribute__((ext_vector_type(16))) float f32x16;
typedef __attribute__((ext_vector_type(4))) int i32x4;
typedef __attribute__((ext_vector_type(8))) int i32x8;

__device__ inline unsigned char f2fp8(float x) {
    __hip_fp8_e4m3 q(x);                    // OCP e4m3 (gfx950), HW convert
    return q.__x;
}

// ---------------- Kernel 1: sequential EMA per label -> fp8 protos ---------
// float4 loads (lane owns 8 contiguous floats), packed 8-B fp8 stores.
__global__ __launch_bounds__(256) void ema_kernel(
    const float* __restrict__ features, const int* __restrict__ labels,
    const float* __restrict__ protos,
    unsigned char* __restrict__ Phi8, float* __restrict__ rowsum) {
    const int row  = blockIdx.x * 4 + (threadIdx.x >> 6);
    const int lane = threadIdx.x & 63;
    if (lane == 0) rowsum[row] = 0.f;

    f32x4 p0 = *(const f32x4*)&protos[(size_t)row * FEAT + lane * 8];
    f32x4 p1 = *(const f32x4*)&protos[(size_t)row * FEAT + lane * 8 + 4];

    for (int c = 0; c < BATCH / 64; ++c) {
        int lab = labels[c * 64 + lane];
        unsigned long long m = __ballot(lab == row);
        while (m) {
            int b = __builtin_ctzll(m);     // earliest remaining sample
            m &= m - 1;
            int s = c * 64 + b;
            f32x4 f0 = *(const f32x4*)&features[(size_t)s * FEAT + lane * 8];
            f32x4 f1 = *(const f32x4*)&features[(size_t)s * FEAT + lane * 8 + 4];
            p0 = p0 * 0.95f + f0 * 0.05f;
            p1 = p1 * 0.95f + f1 * 0.05f;
            float ss = p0[0]*p0[0] + p0[1]*p0[1] + p0[2]*p0[2] + p0[3]*p0[3]
                     + p1[0]*p1[0] + p1[1]*p1[1] + p1[2]*p1[2] + p1[3]*p1[3];
            #pragma unroll
            for (int off = 32; off; off >>= 1) ss += __shfl_xor(ss, off);
            float inv = 1.0f / fmaxf(sqrtf(ss), 1e-12f);
            p0 *= inv; p1 *= inv;
        }
    }
    unsigned long long packed = 0;
    #pragma unroll
    for (int jj = 0; jj < 4; ++jj)
        packed |= (unsigned long long)f2fp8(p0[jj]) << (8 * jj);
    #pragma unroll
    for (int jj = 0; jj < 4; ++jj)
        packed |= (unsigned long long)f2fp8(p1[jj]) << (8 * (jj + 4));
    *(unsigned long long*)&Phi8[(size_t)row * FEAT + lane * 8] = packed;
}

// ---------------- Kernel 2: 256x128 rect Gram tiles, MX-scaled fp8 ---------
// R10/R14 shell (ring-3 K=64 slots, vmcnt(3), 1 barrier/slot, 0-conflict
// XOR-swizzled LDS, 2 blocks/CU) with the MFMA core switched to
// mfma_scale_f32_32x32x64_f8f6f4 @ unit scales: 4 MFMAs/slot/wave instead
// of 32, same LDS bytes -> LDS-read-bound. Wave-tile 64x64 = 2x2 of 32x32.
// A/B fragments use identical lane->(row,k) maps => Gram-correct under any
// true HW k/row permutation (row relabeling is mean-log invariant).
__global__ __launch_bounds__(512, 4) void gemm_disp_kernel(
    const unsigned char* __restrict__ Phi8, float* __restrict__ rowsum) {
    __shared__ __align__(16) char smem[3 * SLOTB];   // 72 KiB

    // XCD-aware swizzle (1056 = 8*132)
    int bid = blockIdx.x;
    int u = (bid & 7) * (NPAIR / 8) + (bid >> 3);
    int i = 0;
    while (u >= NTJ - 2 * i) { u -= NTJ - 2 * i; ++i; }
    const int j = 2 * i + u;                // j >= 2i
    const bool diagovl = ((j >> 1) == i);   // col-range overlaps row-range

    const int w    = threadIdx.x >> 6;      // wave 0..7
    const int lane = threadIdx.x & 63;
    const int wr = w >> 1, wc = w & 1;      // 4x2 waves, 64x64 each
    const int cl = lane & 31;               // row/col within 32x32 fragment
    const int hf = lane >> 5;               // k-half selector

    const int Ibase = i * 256, Jbase = j * 128;

    f32x16 acc[2][2];
    #pragma unroll
    for (int m = 0; m < 2; ++m)
        #pragma unroll
        for (int n = 0; n < 2; ++n)
            #pragma unroll
            for (int t = 0; t < 16; ++t) acc[m][n][t] = 0.f;

    // staging (byte-identical to R10): per slot 24 KB, 3 loads/wave.
    // LDS[row][seg'] holds global seg g = seg' ^ ((row>>1)&3).
    const int srow = lane >> 2;             // 0..15
    const int sseg = (lane & 3) ^ ((lane >> 3) & 3);
    const unsigned char* gA =
        Phi8 + (size_t)(Ibase + w * 32 + srow) * FEAT + sseg * 16;
    const unsigned char* gB =
        Phi8 + (size_t)(Jbase + w * 16 + srow) * FEAT + sseg * 16;

#define STAGE(s)                                                              \
    {                                                                         \
        char* base = smem + ((s) % 3) * SLOTB;                                \
        __builtin_amdgcn_global_load_lds(                                     \
            (const __attribute__((address_space(1))) void*)(gA + (s) * 64),   \
            (__attribute__((address_space(3))) void*)(base + w * 2048),       \
            16, 0, 0);                                                        \
        __builtin_amdgcn_global_load_lds(                                     \
            (const __attribute__((address_space(1))) void*)(gA + 16 * FEAT + (s) * 64), \
            (__attribute__((address_space(3))) void*)(base + w * 2048 + 1024),\
            16, 0, 0);                                                        \
        __builtin_amdgcn_global_load_lds(                                     \
            (const __attribute__((address_space(1))) void*)(gB + (s) * 64),   \
            (__attribute__((address_space(3))) void*)(base + 16384 + w * 1024),\
            16, 0, 0);                                                        \
    }

// Fragment read: lane covers row `row`, global k-bytes [hf*32, hf*32+32)
// = global segs {2hf, 2hf+1}, each stored at seg^((row>>1)&3).
#define RDFRAG(dst, base, row)                                                \
    {                                                                         \
        const int swz_ = (((row) >> 1) & 3);                                  \
        i32x4 lo_ = *(const i32x4*)((base) + (size_t)(row) * 64               \
                                    + ((2 * hf) ^ swz_) * 16);                \
        i32x4 hi_ = *(const i32x4*)((base) + (size_t)(row) * 64               \
                                    + ((2 * hf + 1) ^ swz_) * 16);            \
        _Pragma("unroll")                                                     \
        for (int t_ = 0; t_ < 4; ++t_) { dst[t_] = lo_[t_]; dst[4 + t_] = hi_[t_]; } \
    }

#define MFS(av, bv, mi, ni)                                                   \
    acc[mi][ni] = __builtin_amdgcn_mfma_scale_f32_32x32x64_f8f6f4(            \
        av, bv, acc[mi][ni], 0, 0, 0, UNITSC, 0, UNITSC);

#define SLOT(s, TAIL)                                                         \
    {                                                                         \
        const char* As = smem + ((s) % 3) * SLOTB;                            \
        const char* Bs = As + 16384;                                          \
        i32x8 a0, a1, b0, b1;                                                 \
        RDFRAG(b0, Bs, wc * 64 +  0 + cl)                                     \
        RDFRAG(b1, Bs, wc * 64 + 32 + cl)                                     \
        RDFRAG(a0, As, wr * 64 +  0 + cl)                                     \
        RDFRAG(a1, As, wr * 64 + 32 + cl)                                     \
        __builtin_amdgcn_s_setprio(1);                                        \
        MFS(a0, b0, 0, 0) MFS(a1, b0, 1, 0)                                   \
        MFS(a0, b1, 0, 1) MFS(a1, b1, 1, 1)                                   \
        __builtin_amdgcn_s_setprio(0);                                        \
        TAIL                                                                  \
    }

#define TAIL_MID(s)                                                           \
    STAGE((s) + 2)                                                            \
    asm volatile("s_waitcnt vmcnt(3)" ::: "memory");                          \
    __builtin_amdgcn_s_barrier();
#define TAIL_6                                                                \
    asm volatile("s_waitcnt vmcnt(0)" ::: "memory");                          \
    __builtin_amdgcn_s_barrier();
#define TAIL_7

    // prologue: stage slots 0,1; wait slot 0 landed (slot 1 stays in flight)
    STAGE(0) STAGE(1)
    asm volatile("s_waitcnt vmcnt(3)" ::: "memory");
    __builtin_amdgcn_s_barrier();

    SLOT(0, TAIL_MID(0)) SLOT(1, TAIL_MID(1)) SLOT(2, TAIL_MID(2))
    SLOT(3, TAIL_MID(3)) SLOT(4, TAIL_MID(4)) SLOT(5, TAIL_MID(5))
    SLOT(6, TAIL_6)
    SLOT(7, TAIL_7)

    // epilogue: e = exp(10*S); zero exact diagonal on overlap blocks.
    // 32x32 C/D layout (HW-verified, shape-determined even for f8f6f4):
    // col = cl, row = (t&3) + 8*(t>>2) + 4*hf.
    #pragma unroll
    for (int m = 0; m < 2; ++m)
        #pragma unroll
        for (int n = 0; n < 2; ++n)
            #pragma unroll
            for (int t = 0; t < 16; ++t) {
                int grow = wr * 64 + m * 32 + (t & 3) + 8 * (t >> 2) + 4 * hf;
                int gcol = wc * 64 + n * 32 + cl;
                float v = __expf(acc[m][n][t] * 10.0f);
                if (diagovl && (Ibase + grow) == (Jbase + gcol)) v = 0.f;
                acc[m][n][t] = v;
            }

    // row credit: reduce over the 32 cols held by this half-wave's lanes
    #pragma unroll
    for (int m = 0; m < 2; ++m) {
        #pragma unroll
        for (int t = 0; t < 16; ++t) {
            float rs = acc[m][0][t] + acc[m][1][t];
            #pragma unroll
            for (int off = 1; off < 32; off <<= 1) rs += __shfl_xor(rs, off);
            if (cl == 0)
                atomicAdd(&rowsum[Ibase + wr * 64 + m * 32 +
                                  (t & 3) + 8 * (t >> 2) + 4 * hf], rs);
        }
    }

    // col credit (mirror entries; skip when mirror computed in-block)
    if (!diagovl) {
        #pragma unroll
        for (int n = 0; n < 2; ++n) {
            float cs = 0.f;
            #pragma unroll
            for (int m = 0; m < 2; ++m)
                #pragma unroll
                for (int t = 0; t < 16; ++t) cs += acc[m][n][t];
            cs += __shfl_xor(cs, 32);       // combine the two row-halves
            if (hf == 0)
                atomicAdd(&rowsum[Jbase + wc * 64 + n * 32 + cl], cs);
        }
    }
}

// ---------------- Kernel 3: loss = mean(log(rowsum / (n-1))) ---------------
__global__ __launch_bounds__(512) void loss_kernel(
    const float* __restrict__ rowsum, float* __restrict__ out) {
    __shared__ float red[8];
    float s = 0.f;
    for (int i = threadIdx.x; i < N_CLS; i += 512)
        s += logf(rowsum[i] * (1.0f / (float)(N_CLS - 1)));
    #pragma unroll
    for (int off = 32; off; off >>= 1) s += __shfl_xor(s, off);
    if ((threadIdx.x & 63) == 0) red[threadIdx.x >> 6] = s;
    __syncthreads();
    if (threadIdx.x == 0) {
        float tot = 0.f;
        #pragma unroll
        for (int i = 0; i < 8; ++i) tot += red[i];
        out[0] = tot * (1.0f / (float)N_CLS);
    }
}

extern "C" void kernel_launch(void* const* d_in, const int* in_sizes, int n_in,
                              void* d_out, int out_size, void* d_ws, size_t ws_size,
                              hipStream_t stream) {
    (void)in_sizes; (void)n_in; (void)out_size; (void)ws_size;
    const float* features = (const float*)d_in[0];
    const int*   labels   = (const int*)d_in[1];
    const float* protos   = (const float*)d_in[2];
    float* out = (float*)d_out;

    unsigned char* Phi8 = (unsigned char*)d_ws;                     // 4 MiB
    float* rowsum = (float*)(Phi8 + (size_t)N_CLS * FEAT);          // 32 KiB

    ema_kernel<<<N_CLS / 4, 256, 0, stream>>>(features, labels, protos, Phi8, rowsum);
    gemm_disp_kernel<<<NPAIR, 512, 0, stream>>>(Phi8, rowsum);
    loss_kernel<<<1, 512, 0, stream>>>(rowsum, out);
}